// Round 17
// baseline (57.353 us; speedup 1.0000x reference)
//
#include <hip/hip_runtime.h>
#include <stdint.h>

// Problem constants
#define D_DIM 512
#define B_ROWS 4096
#define N_ROWS 8192
// (1/TEMPERATURE) * log2(e) : exp(x/T) == exp2(x * SCALE_L2E)
#define SCALE_L2E 14.426950408889634f

#define NST 16                      // K steps of 32 (one 16x16x32 MFMA round each)
// 64-row tiles: 128. Supers of 16 tiles (8 supers of 1024 rows).
// Off-diag super-pairs (SI<SJ): 28, 256 blocks each, first (7168 slots, 256-aligned).
// Diag supers: 8, padded to 160 slots each (136 used), appended (starts 32-aligned).
// NBLK = 7168 + 1280 = 8448 = 8 * 1056; 1056 % 32 == 0 -> every XCD chunk and super
// start is 32-aligned, so each CU sees a FIXED r = s%32 within any off-diag super.
#define NOFF (28 * 256)
#define NBLK (NOFF + 8 * 160)

typedef __attribute__((ext_vector_type(4))) float f32x4;
typedef long f8x8;                  // 8 fp8 bytes = 2 VGPRs (one K=32 MFMA operand)

// ---------------- K1: normalize rows -> fp8 e4m3 Zn ([hc][row][32B] planes), fp32 pos;
//                     also zeros the rowsum accumulator (blocks 0..7) ----------------------
// Zn layout: [hc=0..15][row=0..8191][32 B] (plane = 256 KiB, total 4 MiB). A K=32 MFMA
// fragment load (row = l15 + 16*mi, k-seg = lhi*8) is a contiguous dwordx2 per lane,
// 128 B per 16-lane group -> perfectly coalesced.
__global__ __launch_bounds__(256) void k_normalize(const float* __restrict__ zi,
                                                   const float* __restrict__ zj,
                                                   unsigned char* __restrict__ Zn,
                                                   float* __restrict__ pos,
                                                   float* __restrict__ rowsum_g) {
    const int t = threadIdx.x;
    if (blockIdx.x < 8) {  // zero rowsum (runs before k_gemm in-stream; no race)
        float4 z = {0.0f, 0.0f, 0.0f, 0.0f};
        *(float4*)(rowsum_g + blockIdx.x * 1024 + t * 4) = z;
    }
    const int lane = t & 63;
    const int i = blockIdx.x * 4 + (t >> 6);
    const float* pa = zi + (size_t)i * D_DIM + lane * 8;
    const float* pb = zj + (size_t)i * D_DIM + lane * 8;
    const float4 a0 = *(const float4*)pa;
    const float4 a1 = *(const float4*)(pa + 4);
    const float4 b0 = *(const float4*)pb;
    const float4 b1 = *(const float4*)(pb + 4);
    float ssi = a0.x*a0.x + a0.y*a0.y + a0.z*a0.z + a0.w*a0.w
              + a1.x*a1.x + a1.y*a1.y + a1.z*a1.z + a1.w*a1.w;
    float ssj = b0.x*b0.x + b0.y*b0.y + b0.z*b0.z + b0.w*b0.w
              + b1.x*b1.x + b1.y*b1.y + b1.z*b1.z + b1.w*b1.w;
    float dt  = a0.x*b0.x + a0.y*b0.y + a0.z*b0.z + a0.w*b0.w
              + a1.x*b1.x + a1.y*b1.y + a1.z*b1.z + a1.w*b1.w;
    #pragma unroll
    for (int off = 1; off < 64; off <<= 1) {
        ssi += __shfl_xor(ssi, off);
        ssj += __shfl_xor(ssj, off);
        dt  += __shfl_xor(dt,  off);
    }
    const float si = 1.0f / fmaxf(sqrtf(ssi), 1e-12f);
    const float sj = 1.0f / fmaxf(sqrtf(ssj), 1e-12f);
    // pack 8 normalized values (k = lane*8 .. +8) -> 8 fp8 e4m3 (HW RNE)
    uint2 pi8, pj8;
    {
        int w0 = 0, w1 = 0;
        w0 = __builtin_amdgcn_cvt_pk_fp8_f32(a0.x * si, a0.y * si, w0, false);
        w0 = __builtin_amdgcn_cvt_pk_fp8_f32(a0.z * si, a0.w * si, w0, true);
        w1 = __builtin_amdgcn_cvt_pk_fp8_f32(a1.x * si, a1.y * si, w1, false);
        w1 = __builtin_amdgcn_cvt_pk_fp8_f32(a1.z * si, a1.w * si, w1, true);
        pi8.x = (unsigned)w0; pi8.y = (unsigned)w1;
        w0 = 0; w1 = 0;
        w0 = __builtin_amdgcn_cvt_pk_fp8_f32(b0.x * sj, b0.y * sj, w0, false);
        w0 = __builtin_amdgcn_cvt_pk_fp8_f32(b0.z * sj, b0.w * sj, w0, true);
        w1 = __builtin_amdgcn_cvt_pk_fp8_f32(b1.x * sj, b1.y * sj, w1, false);
        w1 = __builtin_amdgcn_cvt_pk_fp8_f32(b1.z * sj, b1.w * sj, w1, true);
        pj8.x = (unsigned)w0; pj8.y = (unsigned)w1;
    }
    // lane covers k = lane*8..+7 -> hc = lane>>2, 8B-seg = lane&3
    const size_t PLANE = (size_t)N_ROWS * 32;  // bytes per hc-plane
    const size_t off0  = (size_t)(lane >> 2) * PLANE + (lane & 3) * 8;
    *(uint2*)(Zn + off0 + (size_t)i * 32) = pi8;
    *(uint2*)(Zn + off0 + (size_t)(B_ROWS + i) * 32) = pj8;
    if (lane == 0) pos[i] = 20.0f * dt * si * sj;  // positive logit counted twice: 2*dot/T
}

// ---------------- K2: symmetric fused S = Zn·Zn^T (fp8 MFMA) + per-row sum(exp(S/T)) ------
// ONE WAVE per block, 64x64 tile pair. NO LDS, no barriers. CU-compact ordering (r14).
// Triple-buffered ring at K=32 step granularity: during MFMA(s), loads for s+1 AND s+2 are
// in flight (2-deep, 64 lines/wave) at 4 waves/SIMD (frags 3x16 + acc 64 + addr ~= 120
// regs) -> 256 lines in flight per SIMD (vs 192 in the r15 structure).
__global__ __launch_bounds__(64, 4) void k_gemm_lse(const unsigned char* __restrict__ Zn,
                                                    float* __restrict__ rowsum_g) {
    const int lane = threadIdx.x & 63;
    const int l15  = lane & 15, lhi = lane >> 4;

    // XCD-aware swizzle (bijective: NBLK % 8 == 0)
    const int s = (blockIdx.x & 7) * (NBLK / 8) + (blockIdx.x >> 3);
    int SI, SJ, di, dj;
    if (s < NOFF) {
        const int sp = s >> 8;       // off-diag super-pair 0..27
        int g = s & 255;
        int a = 0, b = 1;
        for (int k = 0; k < sp; ++k) { if (++b == 8) { ++a; b = a + 1; } }
        SI = a; SJ = b;
        const int q = g >> 5, r = g & 31;
        di = r & 15; dj = (r >> 4) * 8 + q;
    } else {
        int g = s - NOFF;
        const int S = g / 160;
        g = g % 160;
        if (g >= 136) return;        // padding slot
        SI = SJ = S;
        di = 0;
        while (g >= 16 - di) { g -= 16 - di; ++di; }
        dj = di + g;
    }
    const int I = SI * 16 + di, J = SJ * 16 + dj;
    const bool dg = (I == J);
    const int rowB = I * 64;               // wave's first output row
    const int colB = J * 64;               // wave's first output col

    const char* Zb = (const char*)Zn;
    const size_t PLANE = (size_t)N_ROWS * 32;  // bytes per hc-plane

    // fragment base pointers: lane (lhi,l15) reads row (base + l15 + 16*frag), k-seg lhi*8
    const char* pA = Zb + ((size_t)(rowB + l15)) * 32 + lhi * 8;
    const char* pB = Zb + ((size_t)(colB + l15)) * 32 + lhi * 8;

    f8x8 afa[4], bga[4], afb[4], bgb[4], afc[4], bgc[4];

#define LOADAB(dstA, dstB, st)                                                     \
    do {                                                                           \
        const char* _a = pA + (size_t)(st) * PLANE;                                \
        const char* _b = pB + (size_t)(st) * PLANE;                                \
        _Pragma("unroll")                                                          \
        for (int mi = 0; mi < 4; ++mi) dstA[mi] = *(const f8x8*)(_a + mi * 512);   \
        _Pragma("unroll")                                                          \
        for (int ni = 0; ni < 4; ++ni) dstB[ni] = *(const f8x8*)(_b + ni * 512);   \
    } while (0)

#define MFMAAB(srcA, srcB)                                                         \
    do {                                                                           \
        __builtin_amdgcn_s_setprio(1);                                             \
        _Pragma("unroll")                                                          \
        for (int mi = 0; mi < 4; ++mi)                                             \
            _Pragma("unroll")                                                      \
            for (int ni = 0; ni < 4; ++ni)                                         \
                acc[mi][ni] = __builtin_amdgcn_mfma_f32_16x16x32_fp8_fp8(          \
                    srcA[mi], srcB[ni], acc[mi][ni], 0, 0, 0);                     \
        __builtin_amdgcn_s_setprio(0);                                             \
    } while (0)

    f32x4 acc[4][4];
    #pragma unroll
    for (int a = 0; a < 4; ++a)
        #pragma unroll
        for (int b = 0; b < 4; ++b)
            #pragma unroll
            for (int q = 0; q < 4; ++q) acc[a][b][q] = 0.0f;

    // prologue: 3 steps in flight
    LOADAB(afa, bga, 0);
    LOADAB(afb, bgb, 1);
    LOADAB(afc, bgc, 2);

    // steady state: MFMA(s) consumes buffer s%3, then reloads it with step s+3.
    // During MFMA(s), loads for s+1 and s+2 stay outstanding (2-deep lookahead).
    #pragma unroll
    for (int st = 0; st < NST; ++st) {
        if (st % 3 == 0) {
            MFMAAB(afa, bga);
            if (st + 3 < NST) LOADAB(afa, bga, st + 3);
        } else if (st % 3 == 1) {
            MFMAAB(afb, bgb);
            if (st + 3 < NST) LOADAB(afb, bgb, st + 3);
        } else {
            MFMAAB(afc, bgc);
            if (st + 3 < NST) LOADAB(afc, bgc, st + 3);
        }
    }

    // epilogue: e = exp2(S * 10*log2e); C/D layout: col=lane&15, row=(lane>>4)*4+reg
    float colsum[4] = {0.0f, 0.0f, 0.0f, 0.0f};
    #pragma unroll
    for (int mi = 0; mi < 4; ++mi) {
        const int growb = rowB + mi * 16 + lhi * 4;
        float rs[4] = {0.0f, 0.0f, 0.0f, 0.0f};
        if (dg) {
            #pragma unroll
            for (int ni = 0; ni < 4; ++ni) {
                const int gcol = colB + ni * 16 + l15;
                #pragma unroll
                for (int r = 0; r < 4; ++r) {
                    float arg = acc[mi][ni][r] * SCALE_L2E;
                    if (growb + r == gcol) arg = -1e30f;  // diagonal mask -> exp2 = 0
                    rs[r] += exp2f(arg);
                }
            }
        } else {
            #pragma unroll
            for (int ni = 0; ni < 4; ++ni)
                #pragma unroll
                for (int r = 0; r < 4; ++r) {
                    const float e = exp2f(acc[mi][ni][r] * SCALE_L2E);
                    rs[r] += e;
                    colsum[ni] += e;
                }
        }
        // row sums: reduce the 16 lanes sharing lhi; one atomic per (mi, r)
        #pragma unroll
        for (int r = 0; r < 4; ++r) {
            float v = rs[r];
            v += __shfl_xor(v, 1);
            v += __shfl_xor(v, 2);
            v += __shfl_xor(v, 4);
            v += __shfl_xor(v, 8);
            if (l15 == 0) atomicAdd(&rowsum_g[growb + r], v);
        }
    }
    if (!dg) {
        // column sums (symmetry): reduce across lhi groups; lanes lhi==0 hold col l15
        #pragma unroll
        for (int ni = 0; ni < 4; ++ni) {
            float c = colsum[ni];
            c += __shfl_xor(c, 16);
            c += __shfl_xor(c, 32);
            if (lhi == 0)
                atomicAdd(&rowsum_g[colB + ni * 16 + l15], c);
        }
    }
#undef LOADAB
#undef MFMAAB
}

// ---------------- K3: loss = mean(ln(rowsum)) - mean(pos), single block ----------------
__global__ __launch_bounds__(1024) void k_finalize(const float* __restrict__ rowsum_g,
                                                   const float* __restrict__ pos,
                                                   float* __restrict__ out) {
    const int t = threadIdx.x;
    float l = 0.0f, p = 0.0f;
    #pragma unroll
    for (int q = 0; q < N_ROWS / 1024; ++q) l += logf(rowsum_g[t + q * 1024]);
    #pragma unroll
    for (int q = 0; q < B_ROWS / 1024; ++q) p += pos[t + q * 1024];
    #pragma unroll
    for (int off = 1; off < 64; off <<= 1) {
        l += __shfl_xor(l, off);
        p += __shfl_xor(p, off);
    }
    __shared__ float red[2][16];
    if ((t & 63) == 0) { red[0][t >> 6] = l; red[1][t >> 6] = p; }
    __syncthreads();
    if (t == 0) {
        float L = 0.0f, P = 0.0f;
        #pragma unroll
        for (int q = 0; q < 16; ++q) { L += red[0][q]; P += red[1][q]; }
        out[0] = (L - P) * (1.0f / (float)N_ROWS);
    }
}

extern "C" void kernel_launch(void* const* d_in, const int* in_sizes, int n_in,
                              void* d_out, int out_size, void* d_ws, size_t ws_size,
                              hipStream_t stream) {
    (void)in_sizes; (void)n_in; (void)out_size; (void)ws_size;
    const float* zi = (const float*)d_in[0];
    const float* zj = (const float*)d_in[1];

    // workspace layout
    const size_t ZN_BYTES = (size_t)N_ROWS * D_DIM;  // 4 MiB fp8 (hc-tiled)
    unsigned char* Zn     = (unsigned char*)d_ws;
    float* rowsum_g       = (float*)((char*)d_ws + ZN_BYTES);              // 8192 f32
    float* pos            = (float*)((char*)d_ws + ZN_BYTES + N_ROWS * 4); // 4096 f32

    k_normalize<<<B_ROWS / 4, 256, 0, stream>>>(zi, zj, Zn, pos, rowsum_g);
    k_gemm_lse<<<NBLK, 64, 0, stream>>>(Zn, rowsum_g);
    k_finalize<<<1, 1024, 0, stream>>>(rowsum_g, pos, (float*)d_out);
}